// Round 5
// baseline (337.424 us; speedup 1.0000x reference)
//
#include <hip/hip_runtime.h>

typedef __bf16 bf16;
typedef __bf16 bf16x8 __attribute__((ext_vector_type(8)));
typedef __bf16 bf16x4 __attribute__((ext_vector_type(4)));
typedef float f32x4 __attribute__((ext_vector_type(4)));

static __device__ __forceinline__ f32x4 mfma16(bf16x8 a, bf16x8 b, f32x4 c) {
  return __builtin_amdgcn_mfma_f32_16x16x32_bf16(a, b, c, 0, 0, 0);
}

// pack 8 consecutive f32 -> bf16x8
static __device__ __forceinline__ bf16x8 pk8(f32x4 a, f32x4 b) {
  bf16x8 r;
  r[0] = (bf16)a[0]; r[1] = (bf16)a[1]; r[2] = (bf16)a[2]; r[3] = (bf16)a[3];
  r[4] = (bf16)b[0]; r[5] = (bf16)b[1]; r[6] = (bf16)b[2]; r[7] = (bf16)b[3];
  return r;
}

// ---------------------------------------------------------------- k0: all prep (weights->bf16, rpb gather->bf16, mask->bf16)
__global__ void k0_prep(const float* __restrict__ qw, const float* __restrict__ pw,
                        const float* __restrict__ bt, const int* __restrict__ ri,
                        const float* __restrict__ mask, bf16* __restrict__ wqb,
                        bf16* __restrict__ wpb, bf16* __restrict__ rpb_bf,
                        bf16* __restrict__ mask_bf) {
  const int bid = blockIdx.x, tid = threadIdx.x;
  if (bid < 256) {  // weights
    int t = bid * 256 + tid;
    if (t < 49152) wqb[t] = (bf16)qw[t];
    else wpb[t - 49152] = (bf16)pw[t - 49152];
  } else if (bid < 512) {  // rpb gather: rpb_bf[h][n][key]
    int t = (bid - 256) * 256 + tid;  // n*256+key
    int idx = ri[t];
    f32x4 v = *(const f32x4*)(bt + idx * 4);
#pragma unroll
    for (int h = 0; h < 4; ++h) rpb_bf[h * 65536 + t] = (bf16)v[h];
  } else {  // mask f32 -> bf16
    int i = (bid - 512) * 256 + tid;  // 0..524287, 8 elems each
    f32x4 a = *(const f32x4*)(mask + (size_t)i * 8);
    f32x4 b = *(const f32x4*)(mask + (size_t)i * 8 + 4);
    *(bf16x8*)(mask_bf + (size_t)i * 8) = pk8(a, b);
  }
}

// ---------------------------------------------------------------- k1: fused QKV (LDS-staged x)
// q_s,k_s:(B,H,N,32) bf16 row-major; vt:(B,H,32,N) bf16 row-major (no swizzles)
__global__ void __launch_bounds__(256, 3)
k1_qkv(const float* __restrict__ x, const bf16* __restrict__ wqb,
       const float* __restrict__ qb, bf16* __restrict__ q_s,
       bf16* __restrict__ k_s, bf16* __restrict__ vt) {
  __shared__ bf16 xsm[16384];  // 128 rows x 128, 16B-block xor(row&7) swizzle
  const int tid = threadIdx.x;
  const int wv = tid >> 6, ln = tid & 15, qd = (tid >> 4) & 3;
  const int b = blockIdx.x >> 1, half = blockIdx.x & 1;
  const int rg = wv >> 1, cg = wv & 1;

#pragma unroll
  for (int j = 0; j < 8; ++j) {
    const int bidx = j * 256 + tid;
    const int row = bidx >> 4, c = bidx & 15;
    const float* g = x + (size_t)(b * 256 + half * 128 + row) * 128 + c * 8;
    f32x4 a = *(const f32x4*)g, b2 = *(const f32x4*)(g + 4);
    *(bf16x8*)(xsm + row * 128 + ((c ^ (row & 7)) * 8)) = pk8(a, b2);
  }
  __syncthreads();

  f32x4 acc[4][4];
  bf16x8 xfk[4];

  // ---- q (ch=0) and k (ch=1): D = W.X^T (lane holds 4 consecutive out-channels)
#pragma unroll
  for (int ch = 0; ch < 2; ++ch) {
#pragma unroll
    for (int mt = 0; mt < 4; ++mt)
#pragma unroll
      for (int nt = 0; nt < 4; ++nt) acc[mt][nt] = (f32x4){0.f, 0.f, 0.f, 0.f};
#pragma unroll
    for (int ks = 0; ks < 4; ++ks) {
#pragma unroll
      for (int nt = 0; nt < 4; ++nt) {
        const int row_l = rg * 64 + nt * 16 + ln;
        xfk[nt] = *(const bf16x8*)(xsm + row_l * 128 + (((ks * 4 + qd) ^ (ln & 7)) * 8));
      }
#pragma unroll
      for (int mt = 0; mt < 4; ++mt) {
        bf16x8 wf = *(const bf16x8*)(wqb + (size_t)(ch * 128 + cg * 64 + mt * 16 + ln) * 128 +
                                     ks * 32 + qd * 8);
#pragma unroll
        for (int nt = 0; nt < 4; ++nt) acc[mt][nt] = mfma16(wf, xfk[nt], acc[mt][nt]);
      }
    }
    const float scl = ch ? 1.0f : 0.17677669529663689f;
    bf16* dst = ch ? k_s : q_s;
#pragma unroll
    for (int mt = 0; mt < 4; ++mt) {
      const int c0 = cg * 64 + mt * 16 + qd * 4;
      f32x4 b4 = *(const f32x4*)(qb + ch * 128 + c0);
      const int hh = c0 >> 5, d0 = c0 & 31;
#pragma unroll
      for (int nt = 0; nt < 4; ++nt) {
        const int nr = half * 128 + rg * 64 + nt * 16 + ln;
        bf16x4 o;
#pragma unroll
        for (int r = 0; r < 4; ++r) o[r] = (bf16)((acc[mt][nt][r] + b4[r]) * scl);
        *(bf16x4*)(dst + (size_t)(b * 4 + hh) * 8192 + nr * 32 + d0) = o;
      }
    }
  }

  // ---- v: D = X.W^T (lane holds 4 consecutive rows) -> V^T rows d x 256
#pragma unroll
  for (int nt = 0; nt < 4; ++nt)
#pragma unroll
    for (int mt = 0; mt < 4; ++mt) acc[nt][mt] = (f32x4){0.f, 0.f, 0.f, 0.f};
#pragma unroll
  for (int ks = 0; ks < 4; ++ks) {
#pragma unroll
    for (int nt = 0; nt < 4; ++nt) {
      const int row_l = rg * 64 + nt * 16 + ln;
      xfk[nt] = *(const bf16x8*)(xsm + row_l * 128 + (((ks * 4 + qd) ^ (ln & 7)) * 8));
    }
#pragma unroll
    for (int mt = 0; mt < 4; ++mt) {
      bf16x8 wf = *(const bf16x8*)(wqb + (size_t)(256 + cg * 64 + mt * 16 + ln) * 128 +
                                   ks * 32 + qd * 8);
#pragma unroll
      for (int nt = 0; nt < 4; ++nt) acc[nt][mt] = mfma16(xfk[nt], wf, acc[nt][mt]);
    }
  }
#pragma unroll
  for (int nt = 0; nt < 4; ++nt)
#pragma unroll
    for (int mt = 0; mt < 4; ++mt) {
      const int c = cg * 64 + mt * 16 + ln;
      const float bb = qb[256 + c];
      const int hh = c >> 5, dd = c & 31;
      const int n0 = half * 128 + rg * 64 + nt * 16 + qd * 4;
      bf16x4 o;
#pragma unroll
      for (int r = 0; r < 4; ++r) o[r] = (bf16)(acc[nt][mt][r] + bb);
      *(bf16x4*)(vt + (size_t)(b * 4 + hh) * 8192 + dd * 256 + n0) = o;
    }
}

// ---------------------------------------------------------------- k2: attention, 1 wave per (b,h)
// grid 2048 (= 8 blocks/CU, all co-resident), 64 threads. K and V^T live in registers
// (16 + 16 bf16x8 frags). No __syncthreads anywhere. S^T = K.Q^T orientation:
// lane's logits share one q-row -> softmax = 2 shfl_xor. P transposed via 4KB LDS.
__global__ void __launch_bounds__(64, 2)
k2_attn(const bf16* __restrict__ q_s, const bf16* __restrict__ k_s,
        const bf16* __restrict__ vt, const bf16* __restrict__ mask_bf,
        const bf16* __restrict__ rpb_bf, float* __restrict__ ao) {
  __shared__ bf16 psm[2048];  // 16 q-rows x 128 keys (per-half), xor(ln&7) 16B blocks
  const int tid = threadIdx.x, ln = tid & 15, qd = tid >> 4;
  const int h = blockIdx.x & 3, b = blockIdx.x >> 2, w = b & 63;

  const size_t panel = (size_t)(b * 4 + h) * 8192;
  bf16x8 kf[16], vf[16];
#pragma unroll
  for (int mt = 0; mt < 16; ++mt)  // K rows as A-frags (coalesced 1KB/wave)
    kf[mt] = *(const bf16x8*)(k_s + panel + (mt * 16 + ln) * 32 + qd * 8);
#pragma unroll
  for (int k8 = 0; k8 < 8; ++k8)  // V^T as B-frags
#pragma unroll
    for (int ct = 0; ct < 2; ++ct)
      vf[k8 * 2 + ct] = *(const bf16x8*)(vt + panel + (ct * 16 + ln) * 256 + k8 * 32 + qd * 8);

  const bf16* mrow = mask_bf + (size_t)w * 65536;
  const bf16* rrow = rpb_bf + (size_t)h * 65536;
  const bf16* qp = q_s + panel;
  bf16* pb = psm + ln * 128;

  for (int s = 0; s < 16; ++s) {
    bf16x8 qf = *(const bf16x8*)(qp + (s * 16 + ln) * 32 + qd * 8);
    const int nrow = s * 16 + ln;
    float sum = 0.f;
    f32x4 accO[2];
    accO[0] = (f32x4){0.f, 0.f, 0.f, 0.f};
    accO[1] = (f32x4){0.f, 0.f, 0.f, 0.f};

#pragma unroll
    for (int hk = 0; hk < 2; ++hk) {
      // issue bias loads early so they overlap the MFMAs
      bf16x4 mm[8], rr[8];
#pragma unroll
      for (int i = 0; i < 8; ++i) {
        const int off = nrow * 256 + (hk * 8 + i) * 16 + qd * 4;
        mm[i] = *(const bf16x4*)(mrow + off);
        rr[i] = *(const bf16x4*)(rrow + off);
      }
      f32x4 acc[8];
#pragma unroll
      for (int i = 0; i < 8; ++i) acc[i] = (f32x4){0.f, 0.f, 0.f, 0.f};
#pragma unroll
      for (int i = 0; i < 8; ++i)
        acc[i] = mfma16(kf[hk * 8 + i], qf, acc[i]);  // S^T: key=(hk*8+i)*16+qd*4+r, qrow=ln
#pragma unroll
      for (int i = 0; i < 8; ++i) {  // logits + exp (no max-sub: |logit| < ~6)
        bf16x4 pv;
#pragma unroll
        for (int r = 0; r < 4; ++r) {
          float p = __expf(acc[i][r] + (float)mm[i][r] + (float)rr[i][r]);
          sum += p;
          pv[r] = (bf16)p;
        }
        const int p16 = (i * 2 + (qd >> 1)) ^ (ln & 7);
        *(bf16x4*)(pb + p16 * 8 + (qd & 1) * 4) = pv;  // same-wave: no barrier needed
      }
#pragma unroll
      for (int kt = 0; kt < 4; ++kt) {  // O += P.V for this key-half
        bf16x8 pf = *(const bf16x8*)(pb + (((kt * 4 + qd) ^ (ln & 7)) * 8));
#pragma unroll
        for (int ct = 0; ct < 2; ++ct)
          accO[ct] = mfma16(pf, vf[(hk * 4 + kt) * 2 + ct], accO[ct]);
      }
    }
    sum += __shfl_xor(sum, 16);
    sum += __shfl_xor(sum, 32);
    const float linv = 1.0f / sum;
#pragma unroll
    for (int r = 0; r < 4; ++r) {
      const float lb = __shfl(linv, qd * 4 + r);  // row's denom lives at lane ln==row
      const size_t orow = (size_t)(b * 256 + s * 16 + qd * 4 + r) * 128 + h * 32;
#pragma unroll
      for (int ct = 0; ct < 2; ++ct) ao[orow + ct * 16 + ln] = accO[ct][r] * lb;
    }
  }
}

// ---------------------------------------------------------------- k3: proj (in-place on d_out, LDS-staged)
__global__ void __launch_bounds__(256, 3)
k3_proj(const float* __restrict__ xin, const bf16* __restrict__ wpb,
        const float* __restrict__ pbias, float* __restrict__ out) {
  __shared__ bf16 xsm[16384];
  const int tid = threadIdx.x;
  const int wv = tid >> 6, ln = tid & 15, qd = (tid >> 4) & 3;
  const int rg = wv >> 1, cg = wv & 1;
  const size_t row0 = (size_t)blockIdx.x * 128;

#pragma unroll
  for (int j = 0; j < 8; ++j) {
    const int bidx = j * 256 + tid;
    const int row = bidx >> 4, c = bidx & 15;
    const float* g = xin + (row0 + row) * 128 + c * 8;
    f32x4 a = *(const f32x4*)g, b2 = *(const f32x4*)(g + 4);
    *(bf16x8*)(xsm + row * 128 + ((c ^ (row & 7)) * 8)) = pk8(a, b2);
  }
  __syncthreads();  // also: all in-place reads complete before any store

  f32x4 acc[4][4];
  bf16x8 xfk[4];
#pragma unroll
  for (int mt = 0; mt < 4; ++mt)
#pragma unroll
    for (int nt = 0; nt < 4; ++nt) acc[mt][nt] = (f32x4){0.f, 0.f, 0.f, 0.f};
#pragma unroll
  for (int ks = 0; ks < 4; ++ks) {
#pragma unroll
    for (int nt = 0; nt < 4; ++nt) {
      const int row_l = rg * 64 + nt * 16 + ln;
      xfk[nt] = *(const bf16x8*)(xsm + row_l * 128 + (((ks * 4 + qd) ^ (ln & 7)) * 8));
    }
#pragma unroll
    for (int mt = 0; mt < 4; ++mt) {
      bf16x8 wf = *(const bf16x8*)(wpb + (size_t)(cg * 64 + mt * 16 + ln) * 128 +
                                   ks * 32 + qd * 8);
#pragma unroll
      for (int nt = 0; nt < 4; ++nt) acc[mt][nt] = mfma16(wf, xfk[nt], acc[mt][nt]);
    }
  }
#pragma unroll
  for (int mt = 0; mt < 4; ++mt) {
    const int c0 = cg * 64 + mt * 16 + qd * 4;
    f32x4 b4 = *(const f32x4*)(pbias + c0);
#pragma unroll
    for (int nt = 0; nt < 4; ++nt) {
      f32x4 o;
#pragma unroll
      for (int r = 0; r < 4; ++r) o[r] = acc[mt][nt][r] + b4[r];
      *(f32x4*)(out + (row0 + rg * 64 + nt * 16 + ln) * 128 + c0) = o;
    }
  }
}

// ----------------------------------------------------------------
extern "C" void kernel_launch(void* const* d_in, const int* in_sizes, int n_in,
                              void* d_out, int out_size, void* d_ws, size_t ws_size,
                              hipStream_t stream) {
  const float* x = (const float*)d_in[0];
  const float* mask = (const float*)d_in[1];
  const float* qkv_w = (const float*)d_in[2];
  const float* qkv_b = (const float*)d_in[3];
  const float* proj_w = (const float*)d_in[4];
  const float* proj_b = (const float*)d_in[5];
  const float* bias_table = (const float*)d_in[6];
  const int* rel_idx = (const int*)d_in[7];

  char* ws = (char*)d_ws;
  bf16* q_s = (bf16*)ws;                          // 33.5 MB  (B,H,256,32)
  bf16* k_s = (bf16*)(ws + 33554432ll);           // 33.5 MB  (B,H,256,32)
  bf16* vt = (bf16*)(ws + 67108864ll);            // 33.5 MB  (B,H,32,256)
  bf16* mask_bf = (bf16*)(ws + 100663296ll);      // 8.4 MB   (64,256,256)
  bf16* rpb_bf = (bf16*)(ws + 109051904ll);       // 0.5 MB   (4,256,256)
  bf16* wqb = (bf16*)(ws + 109576192ll);          // 96 KB
  bf16* wpb = wqb + 49152;                        // 32 KB    total ~109.7 MB
  float* ao = (float*)d_out;                      // attention out f32 staged in d_out

  k0_prep<<<dim3(2560), dim3(256), 0, stream>>>(qkv_w, proj_w, bias_table, rel_idx,
                                                mask, wqb, wpb, rpb_bf, mask_bf);
  k1_qkv<<<dim3(1024), dim3(256), 0, stream>>>(x, wqb, qkv_b, q_s, k_s, vt);
  k2_attn<<<dim3(2048), dim3(64), 0, stream>>>(q_s, k_s, vt, mask_bf, rpb_bf, ao);
  k3_proj<<<dim3(1024), dim3(256), 0, stream>>>(ao, wpb, proj_b, (float*)d_out);
}